// Round 2
// baseline (711.760 us; speedup 1.0000x reference)
//
#include <hip/hip_runtime.h>
#include <math.h>

// Laminography forward projector:
//  (1) centered 3D FFT of complex volume (3 passes into d_ws)
//  (2) trilinear Fourier-slice sampling -> d_out (float2)
//  (3) centered inverse 2D FFT, two in-place passes on d_out
// Centered identity (n=256): F[k] = (-1)^k * FFT[(-1)^x u[x]] per axis.

namespace {

// ---------- contiguous-line pass (stride 1), 8 lines/block ----------
template<bool INV>
__global__ __launch_bounds__(256)
void fft_contig(const float2* in, float2* out) {
  __shared__ float sre[8][265];
  __shared__ float sim[8][265];
  __shared__ float twr[128];
  __shared__ float twi[128];
  const int t = threadIdx.x;
  if (t < 128) {
    const float TWO_PI = 6.28318530717958647692f;
    float ang = (INV ? TWO_PI : -TWO_PI) * ((float)t * (1.0f / 256.0f));
    float s, c; sincosf(ang, &s, &c);
    twr[t] = c; twi[t] = s;
  }
  const int l = t >> 5, j0 = t & 31;
  const int base = ((int)blockIdx.x * 8 + l) * 256;

  #pragma unroll
  for (int r = 0; r < 8; r++) {
    int j = j0 + 32 * r;
    float2 v = in[base + j];
    float sgn = (j & 1) ? -1.0f : 1.0f;
    sre[l][j] = v.x * sgn;
    sim[l][j] = v.y * sgn;
  }
  __syncthreads();

  const int line = t >> 5, lane = t & 31;
  #pragma unroll
  for (int s = 0; s < 8; s++) {
    const int half = 128 >> s;
    #pragma unroll
    for (int r = 0; r < 4; r++) {
      int b   = lane + 32 * r;
      int pos = b & (half - 1);
      int grp = b >> (7 - s);
      int i   = (grp << (8 - s)) + pos;
      int j   = i + half;
      float ar = sre[line][i], ai = sim[line][i];
      float br = sre[line][j], bi = sim[line][j];
      sre[line][i] = ar + br;
      sim[line][i] = ai + bi;
      float dr = ar - br, di = ai - bi;
      int mm = pos << s;
      float wr = twr[mm], wi = twi[mm];
      sre[line][j] = dr * wr - di * wi;
      sim[line][j] = dr * wi + di * wr;
    }
    __syncthreads();
  }

  const float scale = INV ? (1.0f / 256.0f) : 1.0f;
  #pragma unroll
  for (int r = 0; r < 8; r++) {
    int j = j0 + 32 * r;
    int rev = (int)(__brev((unsigned)j) >> 24);
    float sgn = (j & 1) ? -scale : scale;
    float2 v;
    v.x = sre[l][rev] * sgn;
    v.y = sim[l][rev] * sgn;
    out[base + j] = v;
  }
}

// ---------- strided pass, 16 contiguous lines/block, float4 I/O ----------
// MODE 1: base = (lineIdx>>8)*65536 + (lineIdx&255), stride 256
// MODE 2: base = lineIdx,                            stride 65536
template<int MODE, bool INV>
__global__ __launch_bounds__(256)
void fft_strided(const float2* in, float2* out) {
  __shared__ float sre[16][266];   // 266 % 32 == 10 -> <=2-way bank aliasing
  __shared__ float sim[16][266];
  __shared__ float twr[128];
  __shared__ float twi[128];
  const int t = threadIdx.x;
  if (t < 128) {
    const float TWO_PI = 6.28318530717958647692f;
    float ang = (INV ? TWO_PI : -TWO_PI) * ((float)t * (1.0f / 256.0f));
    float s, c; sincosf(ang, &s, &c);
    twr[t] = c; twi[t] = s;
  }
  const int lp = (t & 7) * 2;         // line-pair base within block
  const int j0 = t >> 3;              // 32 j-slots
  const int lineIdx0 = (int)blockIdx.x * 16;
  int base, stride;
  if (MODE == 1) { base = (lineIdx0 >> 8) * 65536 + (lineIdx0 & 255); stride = 256;   }
  else           { base = lineIdx0;                                   stride = 65536; }
  const float4* in4  = (const float4*)in;   // base+lp even, stride even -> aligned
  float4*       out4 = (float4*)out;

  #pragma unroll
  for (int r = 0; r < 8; r++) {
    int j = j0 + 32 * r;
    float4 v = in4[(base + j * stride + lp) >> 1];
    float sgn = (j & 1) ? -1.0f : 1.0f;
    sre[lp][j]     = v.x * sgn;
    sim[lp][j]     = v.y * sgn;
    sre[lp + 1][j] = v.z * sgn;
    sim[lp + 1][j] = v.w * sgn;
  }
  __syncthreads();

  const int line = t >> 4, lane = t & 15;
  #pragma unroll
  for (int s = 0; s < 8; s++) {
    const int half = 128 >> s;
    #pragma unroll
    for (int r = 0; r < 8; r++) {
      int b   = lane + 16 * r;
      int pos = b & (half - 1);
      int grp = b >> (7 - s);
      int i   = (grp << (8 - s)) + pos;
      int j   = i + half;
      float ar = sre[line][i], ai = sim[line][i];
      float br = sre[line][j], bi = sim[line][j];
      sre[line][i] = ar + br;
      sim[line][i] = ai + bi;
      float dr = ar - br, di = ai - bi;
      int mm = pos << s;
      float wr = twr[mm], wi = twi[mm];
      sre[line][j] = dr * wr - di * wi;
      sim[line][j] = dr * wi + di * wr;
    }
    __syncthreads();
  }

  const float scale = INV ? (1.0f / 256.0f) : 1.0f;
  #pragma unroll
  for (int r = 0; r < 8; r++) {
    int j = j0 + 32 * r;
    int rev = (int)(__brev((unsigned)j) >> 24);
    float sgn = (j & 1) ? -scale : scale;
    float4 v;
    v.x = sre[lp][rev]     * sgn;
    v.y = sim[lp][rev]     * sgn;
    v.z = sre[lp + 1][rev] * sgn;
    v.w = sim[lp + 1][rev] * sgn;
    out4[(base + j * stride + lp) >> 1] = v;
  }
}

// ---------- trilinear Fourier-slice sampling ----------
// 32x32 detector tile per block; threads (32,8); 4 a-rows per thread.
__global__ __launch_bounds__(256)
void sample_kernel(const float2* __restrict__ F, float2* __restrict__ out,
                   const float* __restrict__ theta, const float* __restrict__ tiltp) {
  const int m = blockIdx.z;
  const int b = blockIdx.x * 32 + threadIdx.x;
  const int a0 = blockIdx.y * 32 + threadIdx.y;
  float th = theta[m];
  float ct = cosf(th), st = sinf(th);
  float tl = tiltp[0];
  float cp = cosf(tl), sp = sinf(tl);
  // e_u = (ct, st, 0); e_v = (-st*cp, ct*cp, sp)
  const float eu0 = ct, eu1 = st;
  const float ev0 = -st * cp, ev1 = ct * cp, ev2 = sp;
  const float bu = (float)(b - 128);

  #pragma unroll
  for (int k = 0; k < 4; k++) {
    const int a = a0 + 8 * k;
    const float av = (float)(a - 128);
    float p0 = bu * eu0 + av * ev0 + 128.0f;
    float p1 = bu * eu1 + av * ev1 + 128.0f;
    float p2 = av * ev2 + 128.0f;
    float f0 = floorf(p0), f1 = floorf(p1), f2 = floorf(p2);
    int x0 = (int)f0, y0 = (int)f1, z0 = (int)f2;
    float fx = p0 - f0, fy = p1 - f1, fz = p2 - f2;
    float accr = 0.0f, acci = 0.0f;
    #pragma unroll
    for (int dx = 0; dx < 2; dx++) {
      int x = x0 + dx;
      bool vx = (x >= 0) && (x < 256);
      int xc = min(max(x, 0), 255);
      float wx = dx ? fx : (1.0f - fx);
      #pragma unroll
      for (int dy = 0; dy < 2; dy++) {
        int y = y0 + dy;
        bool vy = vx && (y >= 0) && (y < 256);
        int yc = min(max(y, 0), 255);
        float wxy = wx * (dy ? fy : (1.0f - fy));
        int rowbase = (xc * 256 + yc) * 256;
        #pragma unroll
        for (int dz = 0; dz < 2; dz++) {
          int z = z0 + dz;
          bool v = vy && (z >= 0) && (z < 256);
          int zc = min(max(z, 0), 255);
          float w = v ? wxy * (dz ? fz : (1.0f - fz)) : 0.0f;
          float2 c = F[rowbase + zc];
          accr += w * c.x;
          acci += w * c.y;
        }
      }
    }
    out[(m * 256 + a) * 256 + b] = make_float2(accr, acci);
  }
}

}  // namespace

extern "C" void kernel_launch(void* const* d_in, const int* in_sizes, int n_in,
                              void* d_out, int out_size, void* d_ws, size_t ws_size,
                              hipStream_t stream) {
  const float2* w  = (const float2*)d_in[0];
  const float*  th = (const float*)d_in[1];
  const float*  tl = (const float*)d_in[2];
  float2* F    = (float2*)d_ws;     // 256^3 complex64 = 128 MiB
  float2* out2 = (float2*)d_out;    // (180,256,256) complex64

  // forward 3D FFT (centered)
  fft_contig<false><<<8192, 256, 0, stream>>>(w, F);          // axis 2 (stride 1)
  fft_strided<1, false><<<4096, 256, 0, stream>>>(F, F);      // axis 1 (stride 256)
  fft_strided<2, false><<<4096, 256, 0, stream>>>(F, F);      // axis 0 (stride 65536)

  // Fourier-slice trilinear sampling -> d_out
  dim3 g(8, 8, 180), blk(32, 8);
  sample_kernel<<<g, blk, 0, stream>>>(F, out2, th, tl);

  // centered inverse 2D FFT per angle, in place
  fft_contig<true><<<5760, 256, 0, stream>>>(out2, out2);     // axis b (stride 1)
  fft_strided<1, true><<<2880, 256, 0, stream>>>(out2, out2); // axis a (stride 256)
}

// Round 3
// 667.268 us; speedup vs baseline: 1.0667x; 1.0667x over previous
//
#include <hip/hip_runtime.h>
#include <hip/hip_fp16.h>
#include <math.h>

// Laminography forward projector:
//  (1) centered 3D FFT of complex volume -> fp16 spectrum in d_ws (64 MiB)
//  (2) trilinear Fourier-slice sampling of fp16 spectrum -> d_out (float2)
//  (3) centered inverse 2D FFT (fp32), two in-place passes on d_out
// Centered identity (n=256): F[k] = (-1)^k * FFT[(-1)^x u[x]] per axis.
// fp16 spectrum: |F| <= ~2.4e4 < 65504; rounding adds ~0.01 abs error to output.

namespace {

union F4H2 { float4 f4; __half2 h2[4]; };

// ---------- pass 1: contiguous lines (stride 1), float2 in -> half2 out ----------
__global__ __launch_bounds__(256)
void fft_contig_f16out(const float2* __restrict__ in, __half2* __restrict__ out) {
  __shared__ float sre[8][265];
  __shared__ float sim[8][265];
  __shared__ float twr[128];
  __shared__ float twi[128];
  const int t = threadIdx.x;
  if (t < 128) {
    const float TWO_PI = 6.28318530717958647692f;
    float ang = -TWO_PI * ((float)t * (1.0f / 256.0f));
    float s, c; sincosf(ang, &s, &c);
    twr[t] = c; twi[t] = s;
  }
  const int l = t >> 5, j0 = t & 31;
  const int base = ((int)blockIdx.x * 8 + l) * 256;

  #pragma unroll
  for (int r = 0; r < 8; r++) {
    int j = j0 + 32 * r;
    float2 v = in[base + j];
    float sgn = (j & 1) ? -1.0f : 1.0f;
    sre[l][j] = v.x * sgn;
    sim[l][j] = v.y * sgn;
  }
  __syncthreads();

  const int line = t >> 5, lane = t & 31;
  #pragma unroll
  for (int s = 0; s < 8; s++) {
    const int half = 128 >> s;
    #pragma unroll
    for (int r = 0; r < 4; r++) {
      int b   = lane + 32 * r;
      int pos = b & (half - 1);
      int grp = b >> (7 - s);
      int i   = (grp << (8 - s)) + pos;
      int j   = i + half;
      float ar = sre[line][i], ai = sim[line][i];
      float br = sre[line][j], bi = sim[line][j];
      sre[line][i] = ar + br;
      sim[line][i] = ai + bi;
      float dr = ar - br, di = ai - bi;
      int mm = pos << s;
      float wr = twr[mm], wi = twi[mm];
      sre[line][j] = dr * wr - di * wi;
      sim[line][j] = dr * wi + di * wr;
    }
    __syncthreads();
  }

  // coalesced half2 store; value for output j sits at LDS col bitrev(j)
  #pragma unroll
  for (int r = 0; r < 8; r++) {
    int j = j0 + 32 * r;
    int rev = (int)(__brev((unsigned)j) >> 24);
    float sgn = (j & 1) ? -1.0f : 1.0f;
    out[base + j] = __float22half2_rn(make_float2(sre[l][rev] * sgn, sim[l][rev] * sgn));
  }
}

// ---------- passes 2,3: strided, in-place half2, 32 contiguous lines/block ----------
// MODE 1 (axis y): base = (lineIdx0>>8)*65536 + (lineIdx0&255), stride 256
// MODE 2 (axis x): base = lineIdx0,                             stride 65536
template<int MODE>
__global__ __launch_bounds__(256)
void fft_strided_f16(__half2* data) {
  __shared__ float sre[32][266];   // 266 % 32 == 10
  __shared__ float sim[32][266];
  __shared__ float twr[128];
  __shared__ float twi[128];
  const int t = threadIdx.x;
  if (t < 128) {
    const float TWO_PI = 6.28318530717958647692f;
    float ang = -TWO_PI * ((float)t * (1.0f / 256.0f));
    float s, c; sincosf(ang, &s, &c);
    twr[t] = c; twi[t] = s;
  }
  const int q  = t & 7;    // line quad: lines 4q..4q+3
  const int jj = t >> 3;   // 0..31
  const int lineIdx0 = (int)blockIdx.x * 32;
  int base, stride;
  if (MODE == 1) { base = (lineIdx0 >> 8) * 65536 + (lineIdx0 & 255); stride = 256;   }
  else           { base = lineIdx0;                                   stride = 65536; }
  float4* d4 = (float4*)data;   // base%4==0, stride%4==0, 4q aligned -> ok

  // load: float4 = 4 consecutive lines' half2 at column j
  #pragma unroll
  for (int r = 0; r < 8; r++) {
    int j = jj + 32 * r;
    float sgn = (j & 1) ? -1.0f : 1.0f;
    F4H2 u; u.f4 = d4[(base + j * stride + 4 * q) >> 2];
    #pragma unroll
    for (int c = 0; c < 4; c++) {
      float2 f = __half22float2(u.h2[c]);
      sre[4 * q + c][j] = f.x * sgn;
      sim[4 * q + c][j] = f.y * sgn;
    }
  }
  __syncthreads();

  const int line = t >> 3, lane = t & 7;
  #pragma unroll
  for (int s = 0; s < 8; s++) {
    const int half = 128 >> s;
    #pragma unroll
    for (int r = 0; r < 16; r++) {
      int b   = lane + 8 * r;
      int pos = b & (half - 1);
      int grp = b >> (7 - s);
      int i   = (grp << (8 - s)) + pos;
      int j   = i + half;
      float ar = sre[line][i], ai = sim[line][i];
      float br = sre[line][j], bi = sim[line][j];
      sre[line][i] = ar + br;
      sim[line][i] = ai + bi;
      float dr = ar - br, di = ai - bi;
      int mm = pos << s;
      float wr = twr[mm], wi = twi[mm];
      sre[line][j] = dr * wr - di * wi;
      sim[line][j] = dr * wi + di * wr;
    }
    __syncthreads();
  }

  // readout: LDS contiguous (conflict-free), global index bit-reversed
  // (strided stores are independent 16B transactions; scatter order is free)
  #pragma unroll
  for (int r = 0; r < 8; r++) {
    int p   = jj + 32 * r;
    int rev = (int)(__brev((unsigned)p) >> 24);
    float sgn = (rev & 1) ? -1.0f : 1.0f;
    F4H2 u;
    #pragma unroll
    for (int c = 0; c < 4; c++) {
      u.h2[c] = __float22half2_rn(make_float2(sre[4 * q + c][p] * sgn,
                                              sim[4 * q + c][p] * sgn));
    }
    d4[(base + rev * stride + 4 * q) >> 2] = u.f4;
  }
}

// ---------- inverse contiguous pass (float2, in-place on d_out) ----------
__global__ __launch_bounds__(256)
void fft_contig_inv(float2* data) {
  __shared__ float sre[8][265];
  __shared__ float sim[8][265];
  __shared__ float twr[128];
  __shared__ float twi[128];
  const int t = threadIdx.x;
  if (t < 128) {
    const float TWO_PI = 6.28318530717958647692f;
    float ang = TWO_PI * ((float)t * (1.0f / 256.0f));
    float s, c; sincosf(ang, &s, &c);
    twr[t] = c; twi[t] = s;
  }
  const int l = t >> 5, j0 = t & 31;
  const int base = ((int)blockIdx.x * 8 + l) * 256;

  #pragma unroll
  for (int r = 0; r < 8; r++) {
    int j = j0 + 32 * r;
    float2 v = data[base + j];
    float sgn = (j & 1) ? -1.0f : 1.0f;
    sre[l][j] = v.x * sgn;
    sim[l][j] = v.y * sgn;
  }
  __syncthreads();

  const int line = t >> 5, lane = t & 31;
  #pragma unroll
  for (int s = 0; s < 8; s++) {
    const int half = 128 >> s;
    #pragma unroll
    for (int r = 0; r < 4; r++) {
      int b   = lane + 32 * r;
      int pos = b & (half - 1);
      int grp = b >> (7 - s);
      int i   = (grp << (8 - s)) + pos;
      int j   = i + half;
      float ar = sre[line][i], ai = sim[line][i];
      float br = sre[line][j], bi = sim[line][j];
      sre[line][i] = ar + br;
      sim[line][i] = ai + bi;
      float dr = ar - br, di = ai - bi;
      int mm = pos << s;
      float wr = twr[mm], wi = twi[mm];
      sre[line][j] = dr * wr - di * wi;
      sim[line][j] = dr * wi + di * wr;
    }
    __syncthreads();
  }

  const float scale = 1.0f / 256.0f;
  #pragma unroll
  for (int r = 0; r < 8; r++) {
    int j = j0 + 32 * r;
    int rev = (int)(__brev((unsigned)j) >> 24);
    float sgn = (j & 1) ? -scale : scale;
    data[base + j] = make_float2(sre[l][rev] * sgn, sim[l][rev] * sgn);
  }
}

// ---------- inverse strided pass (float2, stride 256, 16 lines/block) ----------
__global__ __launch_bounds__(256)
void fft_strided_inv(float2* data) {
  __shared__ float sre[16][266];
  __shared__ float sim[16][266];
  __shared__ float twr[128];
  __shared__ float twi[128];
  const int t = threadIdx.x;
  if (t < 128) {
    const float TWO_PI = 6.28318530717958647692f;
    float ang = TWO_PI * ((float)t * (1.0f / 256.0f));
    float s, c; sincosf(ang, &s, &c);
    twr[t] = c; twi[t] = s;
  }
  const int lp = (t & 7) * 2;
  const int j0 = t >> 3;
  const int lineIdx0 = (int)blockIdx.x * 16;
  const int base = (lineIdx0 >> 8) * 65536 + (lineIdx0 & 255);
  const int stride = 256;
  float4* d4 = (float4*)data;

  #pragma unroll
  for (int r = 0; r < 8; r++) {
    int j = j0 + 32 * r;
    float4 v = d4[(base + j * stride + lp) >> 1];
    float sgn = (j & 1) ? -1.0f : 1.0f;
    sre[lp][j]     = v.x * sgn;
    sim[lp][j]     = v.y * sgn;
    sre[lp + 1][j] = v.z * sgn;
    sim[lp + 1][j] = v.w * sgn;
  }
  __syncthreads();

  const int line = t >> 4, lane = t & 15;
  #pragma unroll
  for (int s = 0; s < 8; s++) {
    const int half = 128 >> s;
    #pragma unroll
    for (int r = 0; r < 8; r++) {
      int b   = lane + 16 * r;
      int pos = b & (half - 1);
      int grp = b >> (7 - s);
      int i   = (grp << (8 - s)) + pos;
      int j   = i + half;
      float ar = sre[line][i], ai = sim[line][i];
      float br = sre[line][j], bi = sim[line][j];
      sre[line][i] = ar + br;
      sim[line][i] = ai + bi;
      float dr = ar - br, di = ai - bi;
      int mm = pos << s;
      float wr = twr[mm], wi = twi[mm];
      sre[line][j] = dr * wr - di * wi;
      sim[line][j] = dr * wi + di * wr;
    }
    __syncthreads();
  }

  const float scale = 1.0f / 256.0f;
  #pragma unroll
  for (int r = 0; r < 8; r++) {
    int p   = j0 + 32 * r;
    int rev = (int)(__brev((unsigned)p) >> 24);
    float sgn = (rev & 1) ? -scale : scale;
    float4 v;
    v.x = sre[lp][p]     * sgn;
    v.y = sim[lp][p]     * sgn;
    v.z = sre[lp + 1][p] * sgn;
    v.w = sim[lp + 1][p] * sgn;
    d4[(base + rev * stride + lp) >> 1] = v;
  }
}

// ---------- trilinear Fourier-slice sampling (fp16 spectrum) ----------
// Round-1 geometry: 16x16 tile, 1 px/thread (best measured: latency-bound, high TLP).
__global__ __launch_bounds__(256)
void sample_f16(const __half2* __restrict__ F, float2* __restrict__ out,
                const float* __restrict__ theta, const float* __restrict__ tiltp) {
  const int m = blockIdx.z;
  const int b = blockIdx.x * 16 + threadIdx.x;
  const int a = blockIdx.y * 16 + threadIdx.y;
  float th = theta[m];
  float ct = cosf(th), st = sinf(th);
  float tl = tiltp[0];
  float cp = cosf(tl), sp = sinf(tl);
  float bu = (float)(b - 128);
  float av = (float)(a - 128);
  float p0 = bu * ct + av * (-st * cp) + 128.0f;
  float p1 = bu * st + av * (ct * cp) + 128.0f;
  float p2 = av * sp + 128.0f;
  float f0 = floorf(p0), f1 = floorf(p1), f2 = floorf(p2);
  int x0 = (int)f0, y0 = (int)f1, z0 = (int)f2;
  float fx = p0 - f0, fy = p1 - f1, fz = p2 - f2;
  float accr = 0.0f, acci = 0.0f;
  #pragma unroll
  for (int dx = 0; dx < 2; dx++) {
    int x = x0 + dx;
    bool vx = (x >= 0) && (x < 256);
    int xc = min(max(x, 0), 255);
    float wx = dx ? fx : (1.0f - fx);
    #pragma unroll
    for (int dy = 0; dy < 2; dy++) {
      int y = y0 + dy;
      bool vy = vx && (y >= 0) && (y < 256);
      int yc = min(max(y, 0), 255);
      float wxy = wx * (dy ? fy : (1.0f - fy));
      int rowbase = (xc * 256 + yc) * 256;
      #pragma unroll
      for (int dz = 0; dz < 2; dz++) {
        int z = z0 + dz;
        bool v = vy && (z >= 0) && (z < 256);
        int zc = min(max(z, 0), 255);
        float w = v ? wxy * (dz ? fz : (1.0f - fz)) : 0.0f;
        float2 c = __half22float2(F[rowbase + zc]);
        accr += w * c.x;
        acci += w * c.y;
      }
    }
  }
  out[(m * 256 + a) * 256 + b] = make_float2(accr, acci);
}

}  // namespace

extern "C" void kernel_launch(void* const* d_in, const int* in_sizes, int n_in,
                              void* d_out, int out_size, void* d_ws, size_t ws_size,
                              hipStream_t stream) {
  const float2* w  = (const float2*)d_in[0];
  const float*  th = (const float*)d_in[1];
  const float*  tl = (const float*)d_in[2];
  __half2* Fh  = (__half2*)d_ws;    // 256^3 half2 = 64 MiB
  float2* out2 = (float2*)d_out;    // (180,256,256) complex64

  // forward 3D FFT (centered) -> fp16 spectrum
  fft_contig_f16out<<<8192, 256, 0, stream>>>(w, Fh);        // axis 2 (stride 1)
  fft_strided_f16<1><<<2048, 256, 0, stream>>>(Fh);          // axis 1 (stride 256)
  fft_strided_f16<2><<<2048, 256, 0, stream>>>(Fh);          // axis 0 (stride 65536)

  // Fourier-slice trilinear sampling -> d_out
  dim3 g(16, 16, 180), blk(16, 16);
  sample_f16<<<g, blk, 0, stream>>>(Fh, out2, th, tl);

  // centered inverse 2D FFT per angle, in place
  fft_contig_inv<<<5760, 256, 0, stream>>>(out2);            // axis b (stride 1)
  fft_strided_inv<<<2880, 256, 0, stream>>>(out2);           // axis a (stride 256)
}